// Round 8
// baseline (203.993 us; speedup 1.0000x reference)
//
#include <hip/hip_runtime.h>

// x volumes: [256,256,256] fp32. Row (d,h) = 256 floats = 64 float4.
// float4-unit offset: d*16384 + h*64 + lane.
//
// 3-axis split: registers roll d (a/b/c own-row planes), LDS holds h (block =
// 8 waves = 8 computed rows + 2 halo staged per d-plane, double-buffered),
// DPP (VALU pipe) handles w+-1 — no ds_permute.
// R7 lesson: 4-wave blocks cost 2.75 DS-ops/voxel + 1.5x halo + prologue 40%
// of loads; pipes summed instead of overlapping -> 47us. 8-wave blocks give
// 1.25x halo, ~1.6 DS/voxel, half the barriers/voxel, 40KiB LDS = 4 blocks/CU
// = 32 waves/CU full static occupancy (launch_bounds(512,8) pins VGPR<=64).
// R3 lesson: no __threadfence / fused finalize (per-XCD L2 writeback storm).
//
// Grid: 32 htiles x 64 d-chunks (4 deep) = 2048 blocks x 512 thr (2x oversub).

#define D_CHUNK 4

__device__ __forceinline__ float dpp_shl1(float x) {   // lane i <- lane i-1 (OOB -> 0)
    return __int_as_float(__builtin_amdgcn_update_dpp(
        0, __float_as_int(x), 0x130, 0xF, 0xF, true)); // wave_shl:1
}
__device__ __forceinline__ float dpp_shr1(float x) {   // lane i <- lane i+1 (OOB -> 0)
    return __int_as_float(__builtin_amdgcn_update_dpp(
        0, __float_as_int(x), 0x138, 0xF, 0xF, true)); // wave_shr:1
}

__global__ __launch_bounds__(512, 8) void grad_loss_kernel(const float* __restrict__ xf1,
                                                           const float* __restrict__ xf2,
                                                           double* __restrict__ acc) {
    const float4* __restrict__ x1 = (const float4*)xf1;
    const float4* __restrict__ x2 = (const float4*)xf2;

    // [buf][input][row-slot][lane]; slot s holds row h0-1+s. Exactly 40 KiB.
    __shared__ float4 plane[2][2][10][64];

    const int tid   = threadIdx.x;
    const int lane  = tid & 63;
    const int wid   = tid >> 6;         // 0..7
    const int htile = blockIdx.x & 31;  // 0..31
    const int dchk  = blockIdx.x >> 5;  // 0..63

    const int h0 = 1 + htile * 8;       // computed rows h0..h0+7 (rows >254 dead)
    const int d0 = 1 + dchk * D_CHUNK;  // computed depths d0..d0+3 (>254 dead)

    const int  h    = h0 + wid;
    const bool live = (h <= 254);
    const int  hrow = (h <= 255) ? h : 255;   // clamped row for loads

    // halo duty: wid0->(h0-1,x1) wid1->(h0-1,x2) wid6->(h0+8,x1) wid7->(h0+8,x2)
    const bool has_halo  = (wid < 2) || (wid > 5);
    const int  halo_row  = (wid < 2) ? (h0 - 1) : ((h0 + 8 <= 255) ? (h0 + 8) : 255);
    const int  halo_slot = (wid < 2) ? 0 : 9;
    const int  halo_inp  = wid & 1;
    const float4* __restrict__ halo4 = halo_inp ? x2 : x1;

    const int own_f4  = hrow * 64 + lane;
    const int halo_f4 = halo_row * 64 + lane;

    // per-voxel w-axis weights (0 = excluded border, 2 = edge-replicated)
    const float ww0 = (lane == 0)  ? 0.0f : 1.0f;   // w==0
    const float ww1 = (lane == 0)  ? 2.0f : 1.0f;   // w==1
    const float ww2 = (lane == 63) ? 2.0f : 1.0f;   // w==254
    const float ww3 = (lane == 63) ? 0.0f : 1.0f;   // w==255
    const float whf = (h == 1 || h == 254) ? 2.0f : 1.0f;

    // ---- prologue
    float4 a1 = x1[(d0 - 1) * 16384 + own_f4];
    float4 a2 = x2[(d0 - 1) * 16384 + own_f4];
    float4 b1 = x1[d0 * 16384 + own_f4];
    float4 b2 = x2[d0 * 16384 + own_f4];
    float4 c1 = x1[(d0 + 1) * 16384 + own_f4];   // d0+1 <= 254 always
    float4 c2 = x2[(d0 + 1) * 16384 + own_f4];
    float4 hb = make_float4(0, 0, 0, 0), hc = hb;
    if (has_halo) {
        hb = halo4[d0 * 16384 + halo_f4];
        hc = halo4[(d0 + 1) * 16384 + halo_f4];
    }

    plane[0][0][wid + 1][lane] = b1;
    plane[0][1][wid + 1][lane] = b2;
    if (has_halo) plane[0][halo_inp][halo_slot][lane] = hb;
    __syncthreads();

    float val = 0.0f;

    #pragma unroll
    for (int i = 0; i < D_CHUNK; ++i) {
        const int d   = d0 + i;
        const int cur = i & 1;
        const int nxt = cur ^ 1;
        const int dn  = (d + 2 <= 255) ? (d + 2) : 255;  // prefetch depth (clamped)

        // prefetch plane d+2 (consumed next iteration)
        float4 n1 = x1[dn * 16384 + own_f4];
        float4 n2 = x2[dn * 16384 + own_f4];
        float4 hn = make_float4(0, 0, 0, 0);
        if (has_halo) hn = halo4[dn * 16384 + halo_f4];

        // stage plane d+1 (already in regs) into LDS[nxt]
        plane[nxt][0][wid + 1][lane] = c1;
        plane[nxt][1][wid + 1][lane] = c2;
        if (has_halo) plane[nxt][halo_inp][halo_slot][lane] = hc;

        // compute depth d from LDS[cur] + a/b/c regs
        if (live && d <= 254) {
            float4 u1 = plane[cur][0][wid][lane];       // row h-1
            float4 v1 = plane[cur][0][wid + 2][lane];   // row h+1
            float4 u2 = plane[cur][1][wid][lane];
            float4 v2 = plane[cur][1][wid + 2][lane];

            float l1 = dpp_shl1(b1.w);   // lane0 -> 0, killed by ww0/ww1 weights
            float r1 = dpp_shr1(b1.x);   // lane63 -> 0, killed by ww2/ww3
            float l2 = dpp_shl1(b2.w);
            float r2 = dpp_shr1(b2.x);

            float gw, gd, gh;
            gw = c1.x - a1.x; gd = v1.x - u1.x; gh = b1.y - l1;
            float m10 = __builtin_amdgcn_sqrtf(gw * gw + gd * gd + gh * gh + 1e-6f);
            gw = c1.y - a1.y; gd = v1.y - u1.y; gh = b1.z - b1.x;
            float m11 = __builtin_amdgcn_sqrtf(gw * gw + gd * gd + gh * gh + 1e-6f);
            gw = c1.z - a1.z; gd = v1.z - u1.z; gh = b1.w - b1.y;
            float m12 = __builtin_amdgcn_sqrtf(gw * gw + gd * gd + gh * gh + 1e-6f);
            gw = c1.w - a1.w; gd = v1.w - u1.w; gh = r1 - b1.z;
            float m13 = __builtin_amdgcn_sqrtf(gw * gw + gd * gd + gh * gh + 1e-6f);

            gw = c2.x - a2.x; gd = v2.x - u2.x; gh = b2.y - l2;
            float m20 = __builtin_amdgcn_sqrtf(gw * gw + gd * gd + gh * gh + 1e-6f);
            gw = c2.y - a2.y; gd = v2.y - u2.y; gh = b2.z - b2.x;
            float m21 = __builtin_amdgcn_sqrtf(gw * gw + gd * gd + gh * gh + 1e-6f);
            gw = c2.z - a2.z; gd = v2.z - u2.z; gh = b2.w - b2.y;
            float m22 = __builtin_amdgcn_sqrtf(gw * gw + gd * gd + gh * gh + 1e-6f);
            gw = c2.w - a2.w; gd = v2.w - u2.w; gh = r2 - b2.z;
            float m23 = __builtin_amdgcn_sqrtf(gw * gw + gd * gd + gh * gh + 1e-6f);

            float inner = ww0 * fabsf(m10 - m20)
                        + ww1 * fabsf(m11 - m21)
                        + ww2 * fabsf(m12 - m22)
                        + ww3 * fabsf(m13 - m23);

            const float wdf = (d == 1 || d == 254) ? 2.0f : 1.0f;
            val += wdf * whf * inner;
        }

        a1 = b1; b1 = c1; c1 = n1;
        a2 = b2; b2 = c2; c2 = n2;
        hc = hn;
        __syncthreads();   // plane[nxt] writes visible; plane[cur] reads done
    }

    // wave-64 reduction
    for (int off = 32; off > 0; off >>= 1)
        val += __shfl_down(val, off, 64);

    // 8 wave sums -> reuse plane LDS (keeps LDS at exactly 40 KiB)
    float* red = (float*)&plane[0][0][0][0];
    if (lane == 0) red[wid] = val;
    __syncthreads();

    if (wid == 0) {
        float s = (lane < 8) ? red[lane] : 0.0f;
        s += __shfl_down(s, 4, 64);
        s += __shfl_down(s, 2, 64);
        s += __shfl_down(s, 1, 64);
        if (lane == 0)
            atomicAdd(&acc[blockIdx.x & 255], (double)s);   // no fence!
    }
}

__global__ void finalize_kernel(const double* __restrict__ acc, float* __restrict__ out) {
    double v = acc[threadIdx.x];   // 256 threads, one slot each
    for (int off = 32; off > 0; off >>= 1)
        v += __shfl_down(v, off, 64);

    __shared__ double smem[4];
    const int lid = threadIdx.x & 63;
    const int wid = threadIdx.x >> 6;
    if (lid == 0) smem[wid] = v;
    __syncthreads();

    if (threadIdx.x == 0) {
        double s = smem[0] + smem[1] + smem[2] + smem[3];
        out[0] = (float)(s / 16777216.0);   // mean over 256^3
    }
}

extern "C" void kernel_launch(void* const* d_in, const int* in_sizes, int n_in,
                              void* d_out, int out_size, void* d_ws, size_t ws_size,
                              hipStream_t stream) {
    const float* x1 = (const float*)d_in[0];
    const float* x2 = (const float*)d_in[1];
    float* out = (float*)d_out;
    double* acc = (double*)d_ws;   // 256 doubles = 2 KiB scratch

    hipMemsetAsync(d_ws, 0, 256 * sizeof(double), stream);
    grad_loss_kernel<<<32 * 64, 512, 0, stream>>>(x1, x2, acc);
    finalize_kernel<<<1, 256, 0, stream>>>(acc, out);
}

// Round 9
// 148.224 us; speedup vs baseline: 1.3763x; 1.3763x over previous
//
#include <hip/hip_runtime.h>

// x volumes: [256,256,256] fp32. Row (d,h) = 256 floats = 64 float4.
// float4-unit offset: d*16384 + h*64 + lane.
//
// 3-axis split: registers roll d (a/b/c own-row planes), LDS holds h (block =
// 8 waves = 8 computed rows + 2 halo staged per d-plane, double-buffered),
// DPP (VALU pipe) handles w+-1 — no ds_permute.
// R8 lesson: __launch_bounds__(512,8) pinned VGPR<=64 < the pipeline's live
// set -> scratch spill storm (WRITE_SIZE 0.13->94 MB, +120 MB fetch, 103us).
// NO min-waves cap here: LDS (40 KiB -> 4 blocks/CU) already bounds residency;
// let the allocator take ~56-72 VGPRs. Spills cost more than waves.
// R7 lesson: 4-wave blocks -> 2.75 DS-ops/voxel + 1.5x halo; 8-wave blocks
// give 1.25x halo, ~1.6 DS/voxel, half the barriers/voxel.
// R3 lesson: no __threadfence / fused finalize (per-XCD L2 writeback storm).
//
// Grid: 32 htiles x 64 d-chunks (4 deep) = 2048 blocks x 512 thr.

#define D_CHUNK 4

__device__ __forceinline__ float dpp_shl1(float x) {   // lane i <- lane i-1 (OOB -> 0)
    return __int_as_float(__builtin_amdgcn_update_dpp(
        0, __float_as_int(x), 0x130, 0xF, 0xF, true)); // wave_shl:1
}
__device__ __forceinline__ float dpp_shr1(float x) {   // lane i <- lane i+1 (OOB -> 0)
    return __int_as_float(__builtin_amdgcn_update_dpp(
        0, __float_as_int(x), 0x138, 0xF, 0xF, true)); // wave_shr:1
}

__global__ __launch_bounds__(512) void grad_loss_kernel(const float* __restrict__ xf1,
                                                        const float* __restrict__ xf2,
                                                        double* __restrict__ acc) {
    const float4* __restrict__ x1 = (const float4*)xf1;
    const float4* __restrict__ x2 = (const float4*)xf2;

    // [buf][input][row-slot][lane]; slot s holds row h0-1+s. Exactly 40 KiB.
    __shared__ float4 plane[2][2][10][64];

    const int tid   = threadIdx.x;
    const int lane  = tid & 63;
    const int wid   = tid >> 6;         // 0..7
    const int htile = blockIdx.x & 31;  // 0..31
    const int dchk  = blockIdx.x >> 5;  // 0..63

    const int h0 = 1 + htile * 8;       // computed rows h0..h0+7 (rows >254 dead)
    const int d0 = 1 + dchk * D_CHUNK;  // computed depths d0..d0+3 (>254 dead)

    const int  h    = h0 + wid;
    const bool live = (h <= 254);
    const int  hrow = (h <= 255) ? h : 255;   // clamped row for loads

    // halo duty: wid0->(h0-1,x1) wid1->(h0-1,x2) wid6->(h0+8,x1) wid7->(h0+8,x2)
    const bool has_halo  = (wid < 2) || (wid > 5);
    const int  halo_row  = (wid < 2) ? (h0 - 1) : ((h0 + 8 <= 255) ? (h0 + 8) : 255);
    const int  halo_slot = (wid < 2) ? 0 : 9;
    const int  halo_inp  = wid & 1;
    const float4* __restrict__ halo4 = halo_inp ? x2 : x1;

    const int own_f4  = hrow * 64 + lane;
    const int halo_f4 = halo_row * 64 + lane;

    // per-voxel w-axis weights (0 = excluded border, 2 = edge-replicated)
    const float ww0 = (lane == 0)  ? 0.0f : 1.0f;   // w==0
    const float ww1 = (lane == 0)  ? 2.0f : 1.0f;   // w==1
    const float ww2 = (lane == 63) ? 2.0f : 1.0f;   // w==254
    const float ww3 = (lane == 63) ? 0.0f : 1.0f;   // w==255
    const float whf = (h == 1 || h == 254) ? 2.0f : 1.0f;

    // ---- prologue
    float4 a1 = x1[(d0 - 1) * 16384 + own_f4];
    float4 a2 = x2[(d0 - 1) * 16384 + own_f4];
    float4 b1 = x1[d0 * 16384 + own_f4];
    float4 b2 = x2[d0 * 16384 + own_f4];
    float4 c1 = x1[(d0 + 1) * 16384 + own_f4];   // d0+1 <= 254 always
    float4 c2 = x2[(d0 + 1) * 16384 + own_f4];
    float4 hb = make_float4(0, 0, 0, 0), hc = hb;
    if (has_halo) {
        hb = halo4[d0 * 16384 + halo_f4];
        hc = halo4[(d0 + 1) * 16384 + halo_f4];
    }

    plane[0][0][wid + 1][lane] = b1;
    plane[0][1][wid + 1][lane] = b2;
    if (has_halo) plane[0][halo_inp][halo_slot][lane] = hb;
    __syncthreads();

    float val = 0.0f;

    #pragma unroll
    for (int i = 0; i < D_CHUNK; ++i) {
        const int d   = d0 + i;
        const int cur = i & 1;
        const int nxt = cur ^ 1;
        const int dn  = (d + 2 <= 255) ? (d + 2) : 255;  // prefetch depth (clamped)

        // prefetch plane d+2 (consumed next iteration)
        float4 n1 = x1[dn * 16384 + own_f4];
        float4 n2 = x2[dn * 16384 + own_f4];
        float4 hn = make_float4(0, 0, 0, 0);
        if (has_halo) hn = halo4[dn * 16384 + halo_f4];

        // stage plane d+1 (already in regs) into LDS[nxt]
        plane[nxt][0][wid + 1][lane] = c1;
        plane[nxt][1][wid + 1][lane] = c2;
        if (has_halo) plane[nxt][halo_inp][halo_slot][lane] = hc;

        // compute depth d from LDS[cur] + a/b/c regs
        if (live && d <= 254) {
            float4 u1 = plane[cur][0][wid][lane];       // row h-1
            float4 v1 = plane[cur][0][wid + 2][lane];   // row h+1
            float4 u2 = plane[cur][1][wid][lane];
            float4 v2 = plane[cur][1][wid + 2][lane];

            float l1 = dpp_shl1(b1.w);   // lane0 -> 0, killed by ww0/ww1 weights
            float r1 = dpp_shr1(b1.x);   // lane63 -> 0, killed by ww2/ww3
            float l2 = dpp_shl1(b2.w);
            float r2 = dpp_shr1(b2.x);

            float gw, gd, gh;
            gw = c1.x - a1.x; gd = v1.x - u1.x; gh = b1.y - l1;
            float m10 = __builtin_amdgcn_sqrtf(gw * gw + gd * gd + gh * gh + 1e-6f);
            gw = c1.y - a1.y; gd = v1.y - u1.y; gh = b1.z - b1.x;
            float m11 = __builtin_amdgcn_sqrtf(gw * gw + gd * gd + gh * gh + 1e-6f);
            gw = c1.z - a1.z; gd = v1.z - u1.z; gh = b1.w - b1.y;
            float m12 = __builtin_amdgcn_sqrtf(gw * gw + gd * gd + gh * gh + 1e-6f);
            gw = c1.w - a1.w; gd = v1.w - u1.w; gh = r1 - b1.z;
            float m13 = __builtin_amdgcn_sqrtf(gw * gw + gd * gd + gh * gh + 1e-6f);

            gw = c2.x - a2.x; gd = v2.x - u2.x; gh = b2.y - l2;
            float m20 = __builtin_amdgcn_sqrtf(gw * gw + gd * gd + gh * gh + 1e-6f);
            gw = c2.y - a2.y; gd = v2.y - u2.y; gh = b2.z - b2.x;
            float m21 = __builtin_amdgcn_sqrtf(gw * gw + gd * gd + gh * gh + 1e-6f);
            gw = c2.z - a2.z; gd = v2.z - u2.z; gh = b2.w - b2.y;
            float m22 = __builtin_amdgcn_sqrtf(gw * gw + gd * gd + gh * gh + 1e-6f);
            gw = c2.w - a2.w; gd = v2.w - u2.w; gh = r2 - b2.z;
            float m23 = __builtin_amdgcn_sqrtf(gw * gw + gd * gd + gh * gh + 1e-6f);

            float inner = ww0 * fabsf(m10 - m20)
                        + ww1 * fabsf(m11 - m21)
                        + ww2 * fabsf(m12 - m22)
                        + ww3 * fabsf(m13 - m23);

            const float wdf = (d == 1 || d == 254) ? 2.0f : 1.0f;
            val += wdf * whf * inner;
        }

        a1 = b1; b1 = c1; c1 = n1;
        a2 = b2; b2 = c2; c2 = n2;
        hc = hn;
        __syncthreads();   // plane[nxt] writes visible; plane[cur] reads done
    }

    // wave-64 reduction
    for (int off = 32; off > 0; off >>= 1)
        val += __shfl_down(val, off, 64);

    // 8 wave sums -> reuse plane LDS (keeps LDS at exactly 40 KiB)
    float* red = (float*)&plane[0][0][0][0];
    if (lane == 0) red[wid] = val;
    __syncthreads();

    if (wid == 0) {
        float s = (lane < 8) ? red[lane] : 0.0f;
        s += __shfl_down(s, 4, 64);
        s += __shfl_down(s, 2, 64);
        s += __shfl_down(s, 1, 64);
        if (lane == 0)
            atomicAdd(&acc[blockIdx.x & 255], (double)s);   // no fence!
    }
}

__global__ void finalize_kernel(const double* __restrict__ acc, float* __restrict__ out) {
    double v = acc[threadIdx.x];   // 256 threads, one slot each
    for (int off = 32; off > 0; off >>= 1)
        v += __shfl_down(v, off, 64);

    __shared__ double smem[4];
    const int lid = threadIdx.x & 63;
    const int wid = threadIdx.x >> 6;
    if (lid == 0) smem[wid] = v;
    __syncthreads();

    if (threadIdx.x == 0) {
        double s = smem[0] + smem[1] + smem[2] + smem[3];
        out[0] = (float)(s / 16777216.0);   // mean over 256^3
    }
}

extern "C" void kernel_launch(void* const* d_in, const int* in_sizes, int n_in,
                              void* d_out, int out_size, void* d_ws, size_t ws_size,
                              hipStream_t stream) {
    const float* x1 = (const float*)d_in[0];
    const float* x2 = (const float*)d_in[1];
    float* out = (float*)d_out;
    double* acc = (double*)d_ws;   // 256 doubles = 2 KiB scratch

    hipMemsetAsync(d_ws, 0, 256 * sizeof(double), stream);
    grad_loss_kernel<<<32 * 64, 512, 0, stream>>>(x1, x2, acc);
    finalize_kernel<<<1, 256, 0, stream>>>(acc, out);
}